// Round 1
// baseline (884.016 us; speedup 1.0000x reference)
//
#include <hip/hip_runtime.h>
#include <hip/hip_bf16.h>
#include <math.h>

#define D 128
#define GR 32
#define GC 64
#define LDS_S 132   // padded stride (floats): %4==0 for float4 alignment, %32==4 for bank spread

// ---------------- CSR build ----------------
__global__ __launch_bounds__(256) void zero_ints(int* __restrict__ p, int n) {
  int i = blockIdx.x * 256 + threadIdx.x;
  if (i < n) p[i] = 0;
}

__global__ __launch_bounds__(256) void hist_kernel(const int* __restrict__ rows, int* __restrict__ counts, int E) {
  int e = blockIdx.x * 256 + threadIdx.x;
  if (e < E) atomicAdd(&counts[rows[e]], 1);
}

// block b sums counts[b*1024 .. +1023] -> bsums[b]
__global__ __launch_bounds__(256) void blocksum_kernel(const int* __restrict__ counts, int* __restrict__ bsums, int N) {
  int b = blockIdx.x, t = threadIdx.x;
  int base = b * 1024 + t * 4;
  int s = 0;
#pragma unroll
  for (int q = 0; q < 4; ++q) { int i = base + q; if (i < N) s += counts[i]; }
  for (int off = 32; off; off >>= 1) s += __shfl_xor(s, off);
  __shared__ int wsum[4];
  int w = t >> 6, lane = t & 63;
  if (lane == 0) wsum[w] = s;
  __syncthreads();
  if (t == 0) bsums[b] = wsum[0] + wsum[1] + wsum[2] + wsum[3];
}

// exclusive scan of bsums[NB] (NB <= 128)
__global__ __launch_bounds__(128) void scan_bsums(const int* __restrict__ bsums, int* __restrict__ bpref, int NB) {
  int t = threadIdx.x;
  __shared__ int s[128];
  int v = (t < NB) ? bsums[t] : 0;
  s[t] = v;
  __syncthreads();
  for (int d = 1; d < 128; d <<= 1) {
    int x = (t >= d) ? s[t - d] : 0;
    __syncthreads();
    s[t] += x;
    __syncthreads();
  }
  if (t < NB) bpref[t] = s[t] - v;
}

// full exclusive scan: offsets + cursor copy, offsets[N] = E
__global__ __launch_bounds__(256) void scan_kernel(const int* __restrict__ counts, const int* __restrict__ bpref,
                                                   int* __restrict__ offsets, int* __restrict__ cursor, int N, int E) {
  int b = blockIdx.x, t = threadIdx.x;
  int base = b * 1024 + t * 4;
  int c[4]; int tsum = 0;
#pragma unroll
  for (int q = 0; q < 4; ++q) { int i = base + q; c[q] = (i < N) ? counts[i] : 0; tsum += c[q]; }
  __shared__ int s[256];
  s[t] = tsum;
  __syncthreads();
  for (int d = 1; d < 256; d <<= 1) {
    int x = (t >= d) ? s[t - d] : 0;
    __syncthreads();
    s[t] += x;
    __syncthreads();
  }
  int run = bpref[b] + s[t] - tsum;
#pragma unroll
  for (int q = 0; q < 4; ++q) {
    int i = base + q;
    if (i < N) { offsets[i] = run; cursor[i] = run; }
    run += c[q];
  }
  if (b == 0 && t == 0) offsets[N] = E;
}

__global__ __launch_bounds__(256) void scatter_kernel(const int* __restrict__ rows, const int* __restrict__ cols,
                                                      const float* __restrict__ vals, int* __restrict__ cursor,
                                                      int* __restrict__ ccol, float* __restrict__ cval, int E) {
  int e = blockIdx.x * 256 + threadIdx.x;
  if (e < E) {
    int r = rows[e];
    int pos = atomicAdd(&cursor[r], 1);
    ccol[pos] = cols[e];
    cval[pos] = vals[e];
  }
}

// ---------------- out init: out = scl * l2norm(emb) ----------------
__global__ __launch_bounds__(256) void init_out(const float* __restrict__ Emb, float* __restrict__ out, int N, float scl) {
  int w = threadIdx.x >> 6, lane = threadIdx.x & 63;
  int r = blockIdx.x * 4 + w;
  if (r >= N) return;
  float2 v = *(const float2*)&Emb[(size_t)r * D + 2 * lane];
  float ss = v.x * v.x + v.y * v.y;
  for (int off = 32; off; off >>= 1) ss += __shfl_xor(ss, off);
  float sc = scl / fmaxf(sqrtf(ss), 1e-12f);
  float2 o; o.x = v.x * sc; o.y = v.y * sc;
  *(float2*)&out[(size_t)r * D + 2 * lane] = o;
}

// ---------------- GEMM: Y[r][c] = sum_k X[r][k] * Wl[c][k], Y stored bf16 ----------------
__global__ __launch_bounds__(256) void gemm_kernel(const float* __restrict__ X, const float* __restrict__ Wl,
                                                   __hip_bfloat16* __restrict__ Y, int N) {
  __shared__ float xs[GR * LDS_S];
  __shared__ float wsh[GC * LDS_S];
  int bid = blockIdx.x;
  int cb = bid & 1, rb = bid >> 1;
  int row0 = rb * GR, c0 = cb * GC;
  int tid = threadIdx.x;
  // stage X tile (GR x 128) -> 1024 float4
#pragma unroll
  for (int it = 0; it < 4; ++it) {
    int pos = tid + it * 256;
    int r = pos >> 5, k4 = (pos & 31) << 2;
    int gr = row0 + r;
    float4 v = make_float4(0.f, 0.f, 0.f, 0.f);
    if (gr < N) v = *(const float4*)&X[(size_t)gr * D + k4];
    *(float4*)&xs[r * LDS_S + k4] = v;
  }
  // stage W rows c0..c0+GC-1 -> 2048 float4
#pragma unroll
  for (int it = 0; it < 8; ++it) {
    int pos = tid + it * 256;
    int c = pos >> 5, k4 = (pos & 31) << 2;
    float4 v = *(const float4*)&Wl[(size_t)(c0 + c) * D + k4];
    *(float4*)&wsh[c * LDS_S + k4] = v;
  }
  __syncthreads();
  int ti = tid >> 4, tj = tid & 15;  // rows: 2*ti+i (i<2); cols: c0 + tj + 16*j (j<4)
  float acc[2][4];
#pragma unroll
  for (int i = 0; i < 2; ++i)
#pragma unroll
    for (int j = 0; j < 4; ++j) acc[i][j] = 0.f;
#pragma unroll 4
  for (int k = 0; k < D; k += 4) {
    float4 xv[2], wv[4];
#pragma unroll
    for (int i = 0; i < 2; ++i) xv[i] = *(const float4*)&xs[(2 * ti + i) * LDS_S + k];
#pragma unroll
    for (int j = 0; j < 4; ++j) wv[j] = *(const float4*)&wsh[(tj + 16 * j) * LDS_S + k];
#pragma unroll
    for (int i = 0; i < 2; ++i)
#pragma unroll
      for (int j = 0; j < 4; ++j)
        acc[i][j] += xv[i].x * wv[j].x + xv[i].y * wv[j].y + xv[i].z * wv[j].z + xv[i].w * wv[j].w;
  }
#pragma unroll
  for (int i = 0; i < 2; ++i) {
    int row = row0 + 2 * ti + i;
    if (row < N) {
#pragma unroll
      for (int j = 0; j < 4; ++j)
        Y[(size_t)row * D + c0 + tj + 16 * j] = __float2bfloat16(acc[i][j]);
    }
  }
}

// ---------------- SpMM + ReLU + norm-accumulate ----------------
// one wave per row; lane owns cols {2*lane, 2*lane+1}; Y read as packed bf16x2
__global__ __launch_bounds__(256) void spmm_kernel(const unsigned* __restrict__ Y, const int* __restrict__ offs,
                                                   const int* __restrict__ ccol, const float* __restrict__ cval,
                                                   float* __restrict__ out, float* __restrict__ Xn, int N, float scl) {
  int w = threadIdx.x >> 6, lane = threadIdx.x & 63;
  int r = blockIdx.x * 4 + w;
  if (r >= N) return;
  int s = offs[r], e = offs[r + 1];
  float a0 = 0.f, a1 = 0.f;
  for (int i = s; i < e; ++i) {
    int c = ccol[i];
    float v = cval[i];
    unsigned u = Y[(size_t)c * (D / 2) + lane];
    a0 = fmaf(v, __uint_as_float(u << 16), a0);
    a1 = fmaf(v, __uint_as_float(u & 0xffff0000u), a1);
  }
  a0 = fmaxf(a0, 0.f);
  a1 = fmaxf(a1, 0.f);
  *(float2*)&Xn[(size_t)r * D + 2 * lane] = make_float2(a0, a1);
  float ss = a0 * a0 + a1 * a1;
  for (int off = 32; off; off >>= 1) ss += __shfl_xor(ss, off);
  float sc = scl / fmaxf(sqrtf(ss), 1e-12f);
  float2 o = *(float2*)&out[(size_t)r * D + 2 * lane];
  o.x += sc * a0;
  o.y += sc * a1;
  *(float2*)&out[(size_t)r * D + 2 * lane] = o;
}

// ---------------- launch ----------------
extern "C" void kernel_launch(void* const* d_in, const int* in_sizes, int n_in,
                              void* d_out, int out_size, void* d_ws, size_t ws_size,
                              hipStream_t stream) {
  const int* rows = (const int*)d_in[0];
  const int* cols = (const int*)d_in[1];
  const float* vals = (const float*)d_in[2];
  const float* emb = (const float*)d_in[3];
  const float* W = (const float*)d_in[4];
  float* out = (float*)d_out;

  int E = in_sizes[0];
  int N = in_sizes[3] / D;
  int L = in_sizes[4] / (D * D);
  float scl = 1.0f / (float)(L + 1);

  char* ws = (char*)d_ws;
  size_t off = 0;
  auto take = [&](size_t bytes) -> void* {
    void* p = ws + off;
    off += (bytes + 255) & ~(size_t)255;
    return p;
  };
  float* bufA = (float*)take((size_t)N * D * sizeof(float));            // x_next (fp32)
  __hip_bfloat16* yB = (__hip_bfloat16*)take((size_t)N * D * 2);        // gemm out (bf16)
  int* counts = (int*)take((size_t)(N + 1) * 4);
  int* offsets = (int*)take((size_t)(N + 1) * 4);
  int* cursor = (int*)take((size_t)N * 4);
  int* bsums = (int*)take(512 * 4);
  int* bpref = (int*)take(512 * 4);
  int* ccol = (int*)take((size_t)E * 4);
  float* cval = (float*)take((size_t)E * 4);

  int NB = (N + 1023) / 1024;  // <=128 for this problem size

  zero_ints<<<(N + 256) / 256, 256, 0, stream>>>(counts, N + 1);
  hist_kernel<<<(E + 255) / 256, 256, 0, stream>>>(rows, counts, E);
  blocksum_kernel<<<NB, 256, 0, stream>>>(counts, bsums, N);
  scan_bsums<<<1, 128, 0, stream>>>(bsums, bpref, NB);
  scan_kernel<<<NB, 256, 0, stream>>>(counts, bpref, offsets, cursor, N, E);
  scatter_kernel<<<(E + 255) / 256, 256, 0, stream>>>(rows, cols, vals, cursor, ccol, cval, E);

  init_out<<<(N + 3) / 4, 256, 0, stream>>>(emb, out, N, scl);

  const float* xin = emb;
  for (int l = 0; l < L; ++l) {
    gemm_kernel<<<((N + GR - 1) / GR) * 2, 256, 0, stream>>>(xin, W + (size_t)l * D * D, yB, N);
    spmm_kernel<<<(N + 3) / 4, 256, 0, stream>>>((const unsigned*)yB, offsets, ccol, cval, out, bufA, N, scl);
    xin = bufA;
  }
}

// Round 2
// 644.003 us; speedup vs baseline: 1.3727x; 1.3727x over previous
//
#include <hip/hip_runtime.h>
#include <hip/hip_bf16.h>
#include <math.h>

#define D 128
#define LDS_S 132   // padded stride (floats): %4==0 for float4 alignment, %32==4 for bank spread

// ---------------- CSR build ----------------
__global__ __launch_bounds__(256) void zero_ints(int* __restrict__ p, int n) {
  int i = blockIdx.x * 256 + threadIdx.x;
  if (i < n) p[i] = 0;
}

__global__ __launch_bounds__(256) void hist_kernel(const int* __restrict__ rows, int* __restrict__ counts, int E) {
  int e = blockIdx.x * 256 + threadIdx.x;
  if (e < E) atomicAdd(&counts[rows[e]], 1);
}

// block b sums counts[b*1024 .. +1023] -> bsums[b]
__global__ __launch_bounds__(256) void blocksum_kernel(const int* __restrict__ counts, int* __restrict__ bsums, int N) {
  int b = blockIdx.x, t = threadIdx.x;
  int base = b * 1024 + t * 4;
  int s = 0;
#pragma unroll
  for (int q = 0; q < 4; ++q) { int i = base + q; if (i < N) s += counts[i]; }
  for (int off = 32; off; off >>= 1) s += __shfl_xor(s, off);
  __shared__ int wsum[4];
  int w = t >> 6, lane = t & 63;
  if (lane == 0) wsum[w] = s;
  __syncthreads();
  if (t == 0) bsums[b] = wsum[0] + wsum[1] + wsum[2] + wsum[3];
}

// exclusive scan of bsums[NB] (NB <= 128)
__global__ __launch_bounds__(128) void scan_bsums(const int* __restrict__ bsums, int* __restrict__ bpref, int NB) {
  int t = threadIdx.x;
  __shared__ int s[128];
  int v = (t < NB) ? bsums[t] : 0;
  s[t] = v;
  __syncthreads();
  for (int d = 1; d < 128; d <<= 1) {
    int x = (t >= d) ? s[t - d] : 0;
    __syncthreads();
    s[t] += x;
    __syncthreads();
  }
  if (t < NB) bpref[t] = s[t] - v;
}

// full exclusive scan: offsets + cursor copy, offsets[N] = E
__global__ __launch_bounds__(256) void scan_kernel(const int* __restrict__ counts, const int* __restrict__ bpref,
                                                   int* __restrict__ offsets, int* __restrict__ cursor, int N, int E) {
  int b = blockIdx.x, t = threadIdx.x;
  int base = b * 1024 + t * 4;
  int c[4]; int tsum = 0;
#pragma unroll
  for (int q = 0; q < 4; ++q) { int i = base + q; c[q] = (i < N) ? counts[i] : 0; tsum += c[q]; }
  __shared__ int s[256];
  s[t] = tsum;
  __syncthreads();
  for (int d = 1; d < 256; d <<= 1) {
    int x = (t >= d) ? s[t - d] : 0;
    __syncthreads();
    s[t] += x;
    __syncthreads();
  }
  int run = bpref[b] + s[t] - tsum;
#pragma unroll
  for (int q = 0; q < 4; ++q) {
    int i = base + q;
    if (i < N) { offsets[i] = run; cursor[i] = run; }
    run += c[q];
  }
  if (b == 0 && t == 0) offsets[N] = E;
}

__global__ __launch_bounds__(256) void scatter_kernel(const int* __restrict__ rows, const int* __restrict__ cols,
                                                      const float* __restrict__ vals, int* __restrict__ cursor,
                                                      int* __restrict__ ccol, float* __restrict__ cval, int E) {
  int e = blockIdx.x * 256 + threadIdx.x;
  if (e < E) {
    int r = rows[e];
    int pos = atomicAdd(&cursor[r], 1);
    ccol[pos] = cols[e];
    cval[pos] = vals[e];
  }
}

// ---------------- out init: out = scl * l2norm(emb) ----------------
__global__ __launch_bounds__(256) void init_out(const float* __restrict__ Emb, float* __restrict__ out, int N, float scl) {
  int w = threadIdx.x >> 6, lane = threadIdx.x & 63;
  int r = blockIdx.x * 4 + w;
  if (r >= N) return;
  float2 v = *(const float2*)&Emb[(size_t)r * D + 2 * lane];
  float ss = v.x * v.x + v.y * v.y;
  for (int off = 32; off; off >>= 1) ss += __shfl_xor(ss, off);
  float sc = scl / fmaxf(sqrtf(ss), 1e-12f);
  float2 o; o.x = v.x * sc; o.y = v.y * sc;
  *(float2*)&out[(size_t)r * D + 2 * lane] = o;
}

// ---------------- GEMM: Y[r][c] = sum_k X[r][k] * Wl[c][k], Y stored bf16 ----------------
// 64x64 block tile, 4x4 micro-tile, 256 threads.
__global__ __launch_bounds__(256) void gemm_kernel(const float* __restrict__ X, const float* __restrict__ Wl,
                                                   __hip_bfloat16* __restrict__ Y, int N) {
  __shared__ float xs[64 * LDS_S];
  __shared__ float wsh[64 * LDS_S];
  int bid = blockIdx.x;
  int cb = bid & 1, rb = bid >> 1;
  int row0 = rb * 64, c0 = cb * 64;
  int tid = threadIdx.x;
  // stage X tile (64 x 128) -> 2048 float4, 8 iters
#pragma unroll
  for (int it = 0; it < 8; ++it) {
    int pos = tid + it * 256;
    int r = pos >> 5, k4 = (pos & 31) << 2;
    int gr = row0 + r;
    float4 v = make_float4(0.f, 0.f, 0.f, 0.f);
    if (gr < N) v = *(const float4*)&X[(size_t)gr * D + k4];
    *(float4*)&xs[r * LDS_S + k4] = v;
  }
  // stage W rows c0..c0+63 -> 2048 float4
#pragma unroll
  for (int it = 0; it < 8; ++it) {
    int pos = tid + it * 256;
    int c = pos >> 5, k4 = (pos & 31) << 2;
    float4 v = *(const float4*)&Wl[(size_t)(c0 + c) * D + k4];
    *(float4*)&wsh[c * LDS_S + k4] = v;
  }
  __syncthreads();
  int ti = tid >> 4, tj = tid & 15;  // rows: 4*ti+i (i<4); cols: c0 + tj + 16*j (j<4)
  float acc[4][4];
#pragma unroll
  for (int i = 0; i < 4; ++i)
#pragma unroll
    for (int j = 0; j < 4; ++j) acc[i][j] = 0.f;
#pragma unroll 4
  for (int k = 0; k < D; k += 4) {
    float4 xv[4], wv[4];
#pragma unroll
    for (int i = 0; i < 4; ++i) xv[i] = *(const float4*)&xs[(4 * ti + i) * LDS_S + k];
#pragma unroll
    for (int j = 0; j < 4; ++j) wv[j] = *(const float4*)&wsh[(tj + 16 * j) * LDS_S + k];
#pragma unroll
    for (int i = 0; i < 4; ++i)
#pragma unroll
      for (int j = 0; j < 4; ++j)
        acc[i][j] += xv[i].x * wv[j].x + xv[i].y * wv[j].y + xv[i].z * wv[j].z + xv[i].w * wv[j].w;
  }
#pragma unroll
  for (int i = 0; i < 4; ++i) {
    int row = row0 + 4 * ti + i;
    if (row < N) {
#pragma unroll
      for (int j = 0; j < 4; ++j)
        Y[(size_t)row * D + c0 + tj + 16 * j] = __float2bfloat16(acc[i][j]);
    }
  }
}

// ---------------- SpMM + ReLU + norm-accumulate ----------------
// one wave per row; 4 edge-groups x 16 lanes; lane gathers 16B (8 bf16 cols) per edge.
// unroll 2 -> 8 edges in flight per iteration.
__global__ __launch_bounds__(256) void spmm_kernel(const uint4* __restrict__ Y, const int* __restrict__ offs,
                                                   const int* __restrict__ ccol, const float* __restrict__ cval,
                                                   float* __restrict__ out, float* __restrict__ Xn, int N, float scl) {
  int w = threadIdx.x >> 6, lane = threadIdx.x & 63;
  int r = blockIdx.x * 4 + w;
  if (r >= N) return;
  int g = lane >> 4, l = lane & 15;  // g: edge subgroup, l: col chunk (cols 8l..8l+7)
  int s = offs[r], e = offs[r + 1];
  float acc[8];
#pragma unroll
  for (int k = 0; k < 8; ++k) acc[k] = 0.f;
  for (int base = s; base < e; base += 8) {
    int i0 = base + g, i1 = base + 4 + g;
    int c0 = 0, c1 = 0;
    float f0 = 0.f, f1 = 0.f;
    if (i0 < e) { c0 = ccol[i0]; f0 = cval[i0]; }
    if (i1 < e) { c1 = ccol[i1]; f1 = cval[i1]; }
    uint4 u0 = Y[(size_t)c0 * 16 + l];
    uint4 u1 = Y[(size_t)c1 * 16 + l];
    unsigned uu[8] = {u0.x, u0.y, u0.z, u0.w, u1.x, u1.y, u1.z, u1.w};
    float ff[2] = {f0, f1};
#pragma unroll
    for (int h = 0; h < 2; ++h)
#pragma unroll
      for (int k = 0; k < 4; ++k) {
        unsigned u = uu[h * 4 + k];
        acc[2 * k]     = fmaf(ff[h], __uint_as_float(u << 16), acc[2 * k]);
        acc[2 * k + 1] = fmaf(ff[h], __uint_as_float(u & 0xffff0000u), acc[2 * k + 1]);
      }
  }
  // reduce across the 4 edge-groups (lanes xor 16, 32), then ReLU
#pragma unroll
  for (int k = 0; k < 8; ++k) {
    float a = acc[k];
    a += __shfl_xor(a, 16);
    a += __shfl_xor(a, 32);
    acc[k] = fmaxf(a, 0.f);
  }
  // row norm: sum across the 16 col-chunks
  float ss = 0.f;
#pragma unroll
  for (int k = 0; k < 8; ++k) ss += acc[k] * acc[k];
  ss += __shfl_xor(ss, 1);
  ss += __shfl_xor(ss, 2);
  ss += __shfl_xor(ss, 4);
  ss += __shfl_xor(ss, 8);
  float sc = scl / fmaxf(sqrtf(ss), 1e-12f);
  if (g == 0) {
    size_t p = (size_t)r * D + l * 8;
    *(float4*)&Xn[p]     = make_float4(acc[0], acc[1], acc[2], acc[3]);
    *(float4*)&Xn[p + 4] = make_float4(acc[4], acc[5], acc[6], acc[7]);
    float4 o0 = *(const float4*)&out[p];
    float4 o1 = *(const float4*)&out[p + 4];
    o0.x += sc * acc[0]; o0.y += sc * acc[1]; o0.z += sc * acc[2]; o0.w += sc * acc[3];
    o1.x += sc * acc[4]; o1.y += sc * acc[5]; o1.z += sc * acc[6]; o1.w += sc * acc[7];
    *(float4*)&out[p]     = o0;
    *(float4*)&out[p + 4] = o1;
  }
}

// ---------------- launch ----------------
extern "C" void kernel_launch(void* const* d_in, const int* in_sizes, int n_in,
                              void* d_out, int out_size, void* d_ws, size_t ws_size,
                              hipStream_t stream) {
  const int* rows = (const int*)d_in[0];
  const int* cols = (const int*)d_in[1];
  const float* vals = (const float*)d_in[2];
  const float* emb = (const float*)d_in[3];
  const float* W = (const float*)d_in[4];
  float* out = (float*)d_out;

  int E = in_sizes[0];
  int N = in_sizes[3] / D;
  int L = in_sizes[4] / (D * D);
  float scl = 1.0f / (float)(L + 1);

  char* ws = (char*)d_ws;
  size_t off = 0;
  auto take = [&](size_t bytes) -> void* {
    void* p = ws + off;
    off += (bytes + 255) & ~(size_t)255;
    return p;
  };
  float* bufA = (float*)take((size_t)N * D * sizeof(float));            // x_next (fp32)
  __hip_bfloat16* yB = (__hip_bfloat16*)take((size_t)N * D * 2);        // gemm out (bf16)
  int* counts = (int*)take((size_t)(N + 1) * 4);
  int* offsets = (int*)take((size_t)(N + 1) * 4);
  int* cursor = (int*)take((size_t)N * 4);
  int* bsums = (int*)take(512 * 4);
  int* bpref = (int*)take(512 * 4);
  int* ccol = (int*)take((size_t)E * 4);
  float* cval = (float*)take((size_t)E * 4);

  int NB = (N + 1023) / 1024;  // <=128 for this problem size

  zero_ints<<<(N + 256) / 256, 256, 0, stream>>>(counts, N + 1);
  hist_kernel<<<(E + 255) / 256, 256, 0, stream>>>(rows, counts, E);
  blocksum_kernel<<<NB, 256, 0, stream>>>(counts, bsums, N);
  scan_bsums<<<1, 128, 0, stream>>>(bsums, bpref, NB);
  scan_kernel<<<NB, 256, 0, stream>>>(counts, bpref, offsets, cursor, N, E);
  scatter_kernel<<<(E + 255) / 256, 256, 0, stream>>>(rows, cols, vals, cursor, ccol, cval, E);

  init_out<<<(N + 3) / 4, 256, 0, stream>>>(emb, out, N, scl);

  const float* xin = emb;
  for (int l = 0; l < L; ++l) {
    gemm_kernel<<<((N + 63) / 64) * 2, 256, 0, stream>>>(xin, W + (size_t)l * D * D, yB, N);
    spmm_kernel<<<(N + 3) / 4, 256, 0, stream>>>((const uint4*)yB, offsets, ccol, cval, out, bufA, N, scl);
    xin = bufA;
  }
}

// Round 3
// 520.003 us; speedup vs baseline: 1.7000x; 1.2385x over previous
//
#include <hip/hip_runtime.h>
#include <hip/hip_bf16.h>
#include <math.h>

#define D 128

typedef __attribute__((ext_vector_type(8))) short bf16x8;
typedef __attribute__((ext_vector_type(4))) float f32x4;

static __device__ __forceinline__ unsigned short f2b(float f) {
  __hip_bfloat16 h = __float2bfloat16(f);
  return *reinterpret_cast<unsigned short*>(&h);
}
static __device__ __forceinline__ float blo(unsigned u) { return __uint_as_float(u << 16); }
static __device__ __forceinline__ float bhi(unsigned u) { return __uint_as_float(u & 0xffff0000u); }

// ---------------- CSR build ----------------
__global__ __launch_bounds__(256) void zero_ints(int* __restrict__ p, int n) {
  int i = blockIdx.x * 256 + threadIdx.x;
  if (i < n) p[i] = 0;
}

__global__ __launch_bounds__(256) void hist_kernel(const int* __restrict__ rows, int* __restrict__ counts, int E) {
  int e = blockIdx.x * 256 + threadIdx.x;
  if (e < E) atomicAdd(&counts[rows[e]], 1);
}

__global__ __launch_bounds__(256) void blocksum_kernel(const int* __restrict__ counts, int* __restrict__ bsums, int N) {
  int b = blockIdx.x, t = threadIdx.x;
  int base = b * 1024 + t * 4;
  int s = 0;
#pragma unroll
  for (int q = 0; q < 4; ++q) { int i = base + q; if (i < N) s += counts[i]; }
  for (int off = 32; off; off >>= 1) s += __shfl_xor(s, off);
  __shared__ int wsum[4];
  int w = t >> 6, lane = t & 63;
  if (lane == 0) wsum[w] = s;
  __syncthreads();
  if (t == 0) bsums[b] = wsum[0] + wsum[1] + wsum[2] + wsum[3];
}

__global__ __launch_bounds__(128) void scan_bsums(const int* __restrict__ bsums, int* __restrict__ bpref, int NB) {
  int t = threadIdx.x;
  __shared__ int s[128];
  int v = (t < NB) ? bsums[t] : 0;
  s[t] = v;
  __syncthreads();
  for (int d = 1; d < 128; d <<= 1) {
    int x = (t >= d) ? s[t - d] : 0;
    __syncthreads();
    s[t] += x;
    __syncthreads();
  }
  if (t < NB) bpref[t] = s[t] - v;
}

__global__ __launch_bounds__(256) void scan_kernel(const int* __restrict__ counts, const int* __restrict__ bpref,
                                                   int* __restrict__ offsets, int* __restrict__ cursor, int N, int E) {
  int b = blockIdx.x, t = threadIdx.x;
  int base = b * 1024 + t * 4;
  int c[4]; int tsum = 0;
#pragma unroll
  for (int q = 0; q < 4; ++q) { int i = base + q; c[q] = (i < N) ? counts[i] : 0; tsum += c[q]; }
  __shared__ int s[256];
  s[t] = tsum;
  __syncthreads();
  for (int d = 1; d < 256; d <<= 1) {
    int x = (t >= d) ? s[t - d] : 0;
    __syncthreads();
    s[t] += x;
    __syncthreads();
  }
  int run = bpref[b] + s[t] - tsum;
#pragma unroll
  for (int q = 0; q < 4; ++q) {
    int i = base + q;
    if (i < N) { offsets[i] = run; cursor[i] = run; }
    run += c[q];
  }
  if (b == 0 && t == 0) offsets[N] = E;
}

// packed scatter: one 8B store per edge (col, val-bits)
__global__ __launch_bounds__(256) void scatter_kernel(const int* __restrict__ rows, const int* __restrict__ cols,
                                                      const float* __restrict__ vals, int* __restrict__ cursor,
                                                      uint2* __restrict__ ep, int E) {
  int e = blockIdx.x * 256 + threadIdx.x;
  if (e < E) {
    int r = rows[e];
    int pos = atomicAdd(&cursor[r], 1);
    ep[pos] = make_uint2((unsigned)cols[e], __float_as_uint(vals[e]));
  }
}

// ---------------- fp32 -> bf16 converters ----------------
__global__ __launch_bounds__(256) void conv_bf16(const float* __restrict__ in, unsigned short* __restrict__ outv, int n8) {
  int t = blockIdx.x * 256 + threadIdx.x;
  if (t >= n8) return;
  size_t base = (size_t)t * 8;
  float4 a = *(const float4*)&in[base];
  float4 b = *(const float4*)&in[base + 4];
  ushort4 o0, o1;
  o0.x = f2b(a.x); o0.y = f2b(a.y); o0.z = f2b(a.z); o0.w = f2b(a.w);
  o1.x = f2b(b.x); o1.y = f2b(b.y); o1.z = f2b(b.z); o1.w = f2b(b.w);
  *(ushort4*)&outv[base] = o0;
  *(ushort4*)&outv[base + 4] = o1;
}

// ---------------- GEMM (MFMA bf16): Y[r][c] = sum_k X[r][k] * Wl[c][k] ----------------
// A = W-tile (M=16 cols of output), B = X-tile (N=16 rows), register-direct fragments.
// wave covers 16 X-rows x 64 cols; block = 4 waves = 64 rows x 64 cols; 2 col-halves.
__global__ __launch_bounds__(256) void gemm_mfma(const unsigned short* __restrict__ xb,
                                                 const unsigned short* __restrict__ wb,
                                                 unsigned short* __restrict__ Y, int N) {
  int wave = threadIdx.x >> 6, lane = threadIdx.x & 63;
  int bid = blockIdx.x;
  int ch = bid & 1, rblk = bid >> 1;
  int r0 = rblk * 64 + wave * 16;
  if (r0 >= N) return;
  int c0 = ch * 64;
  int lr = lane & 15, lk = lane >> 4;  // lk in [0,4)
  // X fragments (B operand): lane holds X[r0+lr][lk*8 + 32*s .. +8)
  const unsigned short* xrow = xb + (size_t)(r0 + lr) * D + lk * 8;
  bf16x8 xf[4];
#pragma unroll
  for (int s = 0; s < 4; ++s) xf[s] = *(const bf16x8*)(xrow + 32 * s);
  f32x4 acc[4];
#pragma unroll
  for (int mt = 0; mt < 4; ++mt) acc[mt] = (f32x4){0.f, 0.f, 0.f, 0.f};
#pragma unroll
  for (int mt = 0; mt < 4; ++mt) {
    const unsigned short* wrow = wb + (size_t)(c0 + mt * 16 + lr) * D + lk * 8;
#pragma unroll
    for (int s = 0; s < 4; ++s) {
      bf16x8 wf = *(const bf16x8*)(wrow + 32 * s);
      acc[mt] = __builtin_amdgcn_mfma_f32_16x16x32_bf16(wf, xf[s], acc[mt], 0, 0, 0);
    }
  }
  // D[m][n]: n(col)=lane&15 -> X-row r0+lr ; m(row)=lk*4+reg -> output col
#pragma unroll
  for (int mt = 0; mt < 4; ++mt) {
    ushort4 o;
    o.x = f2b(acc[mt][0]); o.y = f2b(acc[mt][1]); o.z = f2b(acc[mt][2]); o.w = f2b(acc[mt][3]);
    *(ushort4*)&Y[(size_t)(r0 + lr) * D + c0 + mt * 16 + lk * 4] = o;
  }
}

// ---------------- SpMM + ReLU -> bf16 Xn + row norm ----------------
// wave per row; 4 edge-groups x 16 lanes; unroll 4 -> 16 edges in flight; lane gathers 16B per edge.
__global__ __launch_bounds__(256) void spmm_kernel(const uint4* __restrict__ Y, const int* __restrict__ offs,
                                                   const uint2* __restrict__ ep,
                                                   unsigned short* __restrict__ Xn, float* __restrict__ nrm, int N) {
  int w = threadIdx.x >> 6, lane = threadIdx.x & 63;
  int r = blockIdx.x * 4 + w;
  if (r >= N) return;
  int g = lane >> 4, l = lane & 15;
  int s = offs[r], e = offs[r + 1];
  float acc[8];
#pragma unroll
  for (int k = 0; k < 8; ++k) acc[k] = 0.f;
  for (int base = s; base < e; base += 16) {
    uint2 ed[4];
#pragma unroll
    for (int q = 0; q < 4; ++q) {
      int i = base + 4 * q + g;
      ed[q] = (i < e) ? ep[i] : make_uint2(0u, 0u);
    }
    uint4 yv[4];
#pragma unroll
    for (int q = 0; q < 4; ++q) yv[q] = Y[(size_t)ed[q].x * 16 + l];
#pragma unroll
    for (int q = 0; q < 4; ++q) {
      float f = __uint_as_float(ed[q].y);
      unsigned uu[4] = {yv[q].x, yv[q].y, yv[q].z, yv[q].w};
#pragma unroll
      for (int k = 0; k < 4; ++k) {
        acc[2 * k]     = fmaf(f, blo(uu[k]), acc[2 * k]);
        acc[2 * k + 1] = fmaf(f, bhi(uu[k]), acc[2 * k + 1]);
      }
    }
  }
#pragma unroll
  for (int k = 0; k < 8; ++k) {
    float a = acc[k];
    a += __shfl_xor(a, 16);
    a += __shfl_xor(a, 32);
    acc[k] = fmaxf(a, 0.f);
  }
  float ss = 0.f;
#pragma unroll
  for (int k = 0; k < 8; ++k) ss += acc[k] * acc[k];
  ss += __shfl_xor(ss, 1);
  ss += __shfl_xor(ss, 2);
  ss += __shfl_xor(ss, 4);
  ss += __shfl_xor(ss, 8);
  if (lane == 0) nrm[r] = sqrtf(ss);
  if (g == 0) {
    ushort4 o0, o1;
    o0.x = f2b(acc[0]); o0.y = f2b(acc[1]); o0.z = f2b(acc[2]); o0.w = f2b(acc[3]);
    o1.x = f2b(acc[4]); o1.y = f2b(acc[5]); o1.z = f2b(acc[6]); o1.w = f2b(acc[7]);
    size_t p = (size_t)r * D + l * 8;
    *(ushort4*)&Xn[p] = o0;
    *(ushort4*)&Xn[p + 4] = o1;
  }
}

// ---------------- final combine: out = scl*( emb/||emb|| + sum_l x_l / max(nrm_l,eps) ) ----------------
__global__ __launch_bounds__(256) void combine_kernel(const float* __restrict__ emb,
                                                      const unsigned short* __restrict__ x1,
                                                      const unsigned short* __restrict__ x2,
                                                      const unsigned short* __restrict__ x3,
                                                      const float* __restrict__ nrm,
                                                      float* __restrict__ out, int N, float scl) {
  int w = threadIdx.x >> 6, lane = threadIdx.x & 63;
  int r = blockIdx.x * 4 + w;
  if (r >= N) return;
  size_t p = (size_t)r * D + 2 * lane;
  float2 v = *(const float2*)&emb[p];
  float ss = v.x * v.x + v.y * v.y;
  for (int off = 32; off; off >>= 1) ss += __shfl_xor(ss, off);
  float s0 = scl / fmaxf(sqrtf(ss), 1e-12f);
  float i1 = scl / fmaxf(nrm[r], 1e-12f);
  float i2 = scl / fmaxf(nrm[N + r], 1e-12f);
  float i3 = scl / fmaxf(nrm[2 * N + r], 1e-12f);
  unsigned a1 = *(const unsigned*)&x1[p];
  unsigned a2 = *(const unsigned*)&x2[p];
  unsigned a3 = *(const unsigned*)&x3[p];
  float2 o;
  o.x = s0 * v.x + i1 * blo(a1) + i2 * blo(a2) + i3 * blo(a3);
  o.y = s0 * v.y + i1 * bhi(a1) + i2 * bhi(a2) + i3 * bhi(a3);
  *(float2*)&out[p] = o;
}

// ---------------- launch ----------------
extern "C" void kernel_launch(void* const* d_in, const int* in_sizes, int n_in,
                              void* d_out, int out_size, void* d_ws, size_t ws_size,
                              hipStream_t stream) {
  const int* rows = (const int*)d_in[0];
  const int* cols = (const int*)d_in[1];
  const float* vals = (const float*)d_in[2];
  const float* emb = (const float*)d_in[3];
  const float* W = (const float*)d_in[4];
  float* out = (float*)d_out;

  int E = in_sizes[0];
  int N = in_sizes[3] / D;
  int L = in_sizes[4] / (D * D);
  float scl = 1.0f / (float)(L + 1);

  char* ws = (char*)d_ws;
  size_t off = 0;
  auto take = [&](size_t bytes) -> void* {
    void* p = ws + off;
    off += (bytes + 255) & ~(size_t)255;
    return p;
  };
  unsigned short* xb0 = (unsigned short*)take((size_t)N * D * 2);   // bf16 x per layer
  unsigned short* xb1 = (unsigned short*)take((size_t)N * D * 2);
  unsigned short* xb2 = (unsigned short*)take((size_t)N * D * 2);
  unsigned short* xb3 = (unsigned short*)take((size_t)N * D * 2);
  unsigned short* yB  = (unsigned short*)take((size_t)N * D * 2);   // gemm out
  unsigned short* wb  = (unsigned short*)take((size_t)L * D * D * 2);
  float* nrm = (float*)take((size_t)L * N * sizeof(float));
  int* counts = (int*)take((size_t)(N + 1) * 4);
  int* offsets = (int*)take((size_t)(N + 1) * 4);
  int* cursor = (int*)take((size_t)N * 4);
  int* bsums = (int*)take(512 * 4);
  int* bpref = (int*)take(512 * 4);
  uint2* ep = (uint2*)take((size_t)E * 8);

  int NB = (N + 1023) / 1024;

  // CSR build
  zero_ints<<<(N + 256) / 256, 256, 0, stream>>>(counts, N + 1);
  hist_kernel<<<(E + 255) / 256, 256, 0, stream>>>(rows, counts, E);
  blocksum_kernel<<<NB, 256, 0, stream>>>(counts, bsums, N);
  scan_bsums<<<1, 128, 0, stream>>>(bsums, bpref, NB);
  scan_kernel<<<NB, 256, 0, stream>>>(counts, bpref, offsets, cursor, N, E);
  scatter_kernel<<<(E + 255) / 256, 256, 0, stream>>>(rows, cols, vals, cursor, ep, E);

  // bf16 conversions
  int n8x = N * D / 8;
  conv_bf16<<<(n8x + 255) / 256, 256, 0, stream>>>(emb, xb0, n8x);
  int n8w = L * D * D / 8;
  conv_bf16<<<(n8w + 255) / 256, 256, 0, stream>>>(W, wb, n8w);

  unsigned short* xbufs[4] = {xb0, xb1, xb2, xb3};
  int nrb = (N + 63) / 64;
  for (int l = 0; l < L; ++l) {
    gemm_mfma<<<nrb * 2, 256, 0, stream>>>(xbufs[l], wb + (size_t)l * D * D, yB, N);
    spmm_kernel<<<(N + 3) / 4, 256, 0, stream>>>((const uint4*)yB, offsets, ep, xbufs[l + 1], nrm + (size_t)l * N, N);
  }
  combine_kernel<<<(N + 3) / 4, 256, 0, stream>>>(emb, xb1, xb2, xb3, nrm, out, N, scl);
}